// Round 10
// baseline (2429.353 us; speedup 1.0000x reference)
//
#include <hip/hip_runtime.h>
#include <math.h>

#define S_LEN 1024
#define BATCH 2048
#define MTILE 8
#define HID   128
#define NBLK  (BATCH / MTILE)   // 256 blocks -> every CU active
#define INV2048 (1.0f / 2048.0f)

// ws layout, offsets in _Float16 elements. K-extended arrays are [128][160]:
// k<128 = real weights, k=128..130 = (bias, x0-coef, x1-coef), k=131..159 = 0.
#define H_M1H 0
#define H_M1L 20480
#define H_MSH 40960
#define H_MSL 61440
#define H_ASH 81920
#define H_ASL 102400
#define H_WMH 122880     // [128][128] WtauM[:,128:256] hi
#define H_WML 139264
#define H_WBH 155648     // [128][128] WtauAdp[:,128:256] hi
#define H_WBL 172032
#define OFF_PART_F 94208 // float index into ws for per-block partials [256]

typedef _Float16 half8 __attribute__((ext_vector_type(8)));
typedef _Float16 half4 __attribute__((ext_vector_type(4)));
typedef float floatx4 __attribute__((ext_vector_type(4)));

#define MFMA(a, b, c) __builtin_amdgcn_mfma_f32_16x16x32_f16((a), (b), (c), 0, 0, 0)

__device__ __forceinline__ void put_hl(_Float16* ws, int hiBase, int loBase,
                                       int idx, float v) {
  _Float16 hi = (_Float16)v;
  ws[hiBase + idx] = hi;
  ws[loBase + idx] = (_Float16)((v - (float)hi) * 2048.0f);
}

// ---- prep: fold dense->tau coupling + all per-h scalars into f16 hi/lo
// fragment-ready arrays. (unchanged)
__global__ __launch_bounds__(192) void prep(
    const float* __restrict__ W1x, const float* __restrict__ b1x,
    const float* __restrict__ WtauM, const float* __restrict__ btauM,
    const float* __restrict__ WtauAdp, const float* __restrict__ btauAdp,
    _Float16* __restrict__ ws) {
  const int h = blockIdx.x, k = threadIdx.x;
  if (k >= 160) return;
  if (k < 128) {
    float w1 = W1x[h * 130 + 2 + k];
    float s1 = 0.f, s2 = 0.f;
    for (int d = 0; d < 128; ++d) {
      float wd = W1x[d * 130 + 2 + k];
      s1 += WtauM[h * 256 + d] * wd;
      s2 += WtauAdp[h * 256 + d] * wd;
    }
    put_hl(ws, H_M1H, H_M1L, h * 160 + k, w1);
    put_hl(ws, H_MSH, H_MSL, h * 160 + k, s1);
    put_hl(ws, H_ASH, H_ASL, h * 160 + k, s2);
    put_hl(ws, H_WMH, H_WML, h * 128 + k, WtauM[h * 256 + 128 + k]);
    put_hl(ws, H_WBH, H_WBL, h * 128 + k, WtauAdp[h * 256 + 128 + k]);
  } else if (k < 131) {
    const int col = k - 128;   // 0: bias, 1: x0-coef, 2: x1-coef
    float m1v = (col == 0) ? b1x[h] : W1x[h * 130 + (col - 1)];
    float sm = 0.f, sa = 0.f;
    for (int d = 0; d < 128; ++d) {
      float cv = (col == 0) ? b1x[d] : W1x[d * 130 + (col - 1)];
      sm += WtauM[h * 256 + d] * cv;
      sa += WtauAdp[h * 256 + d] * cv;
    }
    if (col == 0) { sm += btauM[h]; sa += btauAdp[h]; }
    put_hl(ws, H_M1H, H_M1L, h * 160 + k, m1v);
    put_hl(ws, H_MSH, H_MSL, h * 160 + k, sm);
    put_hl(ws, H_ASH, H_ASL, h * 160 + k, sa);
  } else {
    put_hl(ws, H_M1H, H_M1L, h * 160 + k, 0.f);
    put_hl(ws, H_MSH, H_MSL, h * 160 + k, 0.f);
    put_hl(ws, H_ASH, H_ASL, h * 160 + k, 0.f);
  }
}

// State slabs: per k-chunk f, 1 KB; half-index (q'*16 + n')*8 + j holds
// B[k=f*32+q'*8+j][n']. n'=0..7: batch HI; n'=8..15: batch LO (x2048);
// spk n'>=8 stays zero. Lane (c,q) reads half-index lane*8 -> identity
// lane-contiguous b128 (m97 fast path, conflict-free).
struct SLds {
  _Float16 spk[2][4][512];
  _Float16 bx[2][512];          // K-ext [1,x0,x1] operand, hi|lo packed
  _Float16 mem[2][4][512];
  _Float16 bbp[2][4][512];
  float red[4][8];
  float red2[8];
};

// 4 waves x 32h (2 A-frag sets each), 1 wave/SIMD, full 512-reg budget.
// The 13 LDS state reads per step are SHARED by both sets; the two sets'
// independent MFMA/VALU chains give the scheduler ILP to overlap pipes.
__global__ __launch_bounds__(256, 1) void snn_main(
    const float* __restrict__ x, const float* __restrict__ y,
    const float* __restrict__ h0m, const float* __restrict__ h0s,
    const float* __restrict__ h0b,
    const float* __restrict__ Wlin, const float* __restrict__ blin,
    const _Float16* __restrict__ W, float* __restrict__ wsout) {
  __shared__ SLds L;

  const int tid  = threadIdx.x;
  const int w    = tid >> 6;      // wave 0..3, owns h-slice [32w, 32w+32)
  const int lane = tid & 63;
  const int c    = lane & 15;     // A-frag m / B-frag n / C col
  const int q    = lane >> 4;
  const int bbase = blockIdx.x * MTILE;
  const bool act = (c < 8);       // cols 8..15 are lo-lanes (no real batch)

  // ---- Register-resident A-frag weights, 2 sets (MFMA-only -> AGPR side)
  // ext-lo coefficient planes (index 4 of *l) dropped: ~2e-5 error, -24 regs.
  half8 m1h[2][5], msh[2][5], ash[2][5];
  half8 m1l[2][4], msl[2][4], asl[2][4];
  half8 wmh[2][4], wml[2][4], wbh[2][4], wbl[2][4];
#pragma unroll
  for (int s = 0; s < 2; ++s) {
    const int hA = w * 32 + s * 16 + c;
#pragma unroll
    for (int f = 0; f < 5; ++f) {
      const int o = hA * 160 + f * 32 + q * 8;
      m1h[s][f] = *(const half8*)&W[H_M1H + o];
      msh[s][f] = *(const half8*)&W[H_MSH + o];
      ash[s][f] = *(const half8*)&W[H_ASH + o];
      if (f < 4) {
        m1l[s][f] = *(const half8*)&W[H_M1L + o];
        msl[s][f] = *(const half8*)&W[H_MSL + o];
        asl[s][f] = *(const half8*)&W[H_ASL + o];
      }
    }
#pragma unroll
    for (int f = 0; f < 4; ++f) {
      const int o = hA * 128 + f * 32 + q * 8;
      wmh[s][f] = *(const half8*)&W[H_WMH + o];
      wml[s][f] = *(const half8*)&W[H_WML + o];
      wbh[s][f] = *(const half8*)&W[H_WBH + o];
      wbl[s][f] = *(const half8*)&W[H_WBL + o];
    }
  }

  // ---- Zero spk (both bufs; lo halves must stay 0) + bx slabs.
  // spk[2][4][512] (2048 u32) + bx[2][512] (512 u32) contiguous: 2560 u32.
  {
    uint32_t* z = (uint32_t*)&L.spk[0][0][0];
#pragma unroll
    for (int j = 0; j < 10; ++j) z[tid + 256 * j] = 0;
  }

  // ---- Per-lane recurrent state: h = w*32 + s*16 + q*4 + r, b = bbase + c
  float memv[8], spk[8], bb[8];
#pragma unroll
  for (int i = 0; i < 8; ++i) { memv[i] = 0.f; spk[i] = 0.f; bb[i] = 0.f; }
  if (act) {
#pragma unroll
    for (int s = 0; s < 2; ++s)
#pragma unroll
      for (int r = 0; r < 4; ++r) {
        const int gi = (bbase + c) * HID + w * 32 + s * 16 + q * 4 + r;
        memv[s * 4 + r] = h0m[gi]; spk[s * 4 + r] = h0s[gi];
        bb[s * 4 + r] = h0b[gi];
      }
  }
  __syncthreads();   // zeros visible before value writes

  // State (h = w*32+s*16+q*4+r) -> B[k=h][n]: chunk fW = w,
  // granule qp = s*2 + (q>>1), j = (q&1)*4 + r.
  int wiH[2], wiL[2];
#pragma unroll
  for (int s = 0; s < 2; ++s) {
    const int qp = s * 2 + (q >> 1);
    wiH[s] = (qp * 16 + c) * 8 + (q & 1) * 4;
    wiL[s] = (qp * 16 + c + 8) * 8 + (q & 1) * 4;
  }
  const int ri = lane * 8;   // identity read offset

  if (act) {   // initial state into buf 0 via the standard write path
#pragma unroll
    for (int s = 0; s < 2; ++s) {
      half4 ps, mh4, ml4, bh4, bl4;
#pragma unroll
      for (int r = 0; r < 4; ++r) {
        const int i = s * 4 + r;
        ps[r] = (_Float16)spk[i];
        float v = memv[i]; _Float16 hi = (_Float16)v;
        mh4[r] = hi; ml4[r] = (_Float16)((v - (float)hi) * 2048.0f);
        v = bb[i]; hi = (_Float16)v;
        bh4[r] = hi; bl4[r] = (_Float16)((v - (float)hi) * 2048.0f);
      }
      *(half4*)&L.spk[0][w][wiH[s]] = ps;
      *(half4*)&L.mem[0][w][wiH[s]] = mh4; *(half4*)&L.mem[0][w][wiL[s]] = ml4;
      *(half4*)&L.bbp[0][w][wiH[s]] = bh4; *(half4*)&L.bbp[0][w][wiL[s]] = bl4;
    }
  }
  if (tid < 16) {  // stage bx[0]: granule q'=0, n'=tid -> half-index tid*8
    float2 x0 = *(const float2*)&x[(size_t)(bbase + (tid & 7)) * 2];
    half8 v;
    if (tid < 8) {
      v = half8{(_Float16)1.0f, (_Float16)x0.x, (_Float16)x0.y, 0, 0, 0, 0, 0};
    } else {
      _Float16 xh0 = (_Float16)x0.x, xh1 = (_Float16)x0.y;
      v = half8{0, (_Float16)((x0.x - (float)xh0) * 2048.0f),
                   (_Float16)((x0.y - (float)xh1) * 2048.0f), 0, 0, 0, 0, 0};
    }
    *(half8*)&L.bx[0][tid * 8] = v;
  }
  __syncthreads();

#pragma unroll 1
  for (int t = 0; t < S_LEN; ++t) {
    const int p = t & 1, pn = p ^ 1;

    floatx4 d1[2], d2[2], m1[2], m2[2], a1[2], a2[2];
#pragma unroll
    for (int s = 0; s < 2; ++s) {
      d1[s] = floatx4{0.f,0.f,0.f,0.f}; d2[s] = floatx4{0.f,0.f,0.f,0.f};
      m1[s] = floatx4{0.f,0.f,0.f,0.f}; m2[s] = floatx4{0.f,0.f,0.f,0.f};
      a1[s] = floatx4{0.f,0.f,0.f,0.f}; a2[s] = floatx4{0.f,0.f,0.f,0.f};
    }

#pragma unroll
    for (int f = 0; f < 4; ++f) {
      half8 S = *(const half8*)&L.spk[p][f][ri];   // [spk | 0]
      half8 M = *(const half8*)&L.mem[p][f][ri];   // [mh  | ml]
      half8 B = *(const half8*)&L.bbp[p][f][ri];   // [bh  | bl]
#pragma unroll
      for (int s = 0; s < 2; ++s) {
        d1[s] = MFMA(m1h[s][f], S, d1[s]);
        d2[s] = MFMA(m1l[s][f], S, d2[s]);
        m1[s] = MFMA(msh[s][f], S, m1[s]);
        m1[s] = MFMA(wmh[s][f], M, m1[s]);   // cols8-15: wmh*ml
        m2[s] = MFMA(msl[s][f], S, m2[s]);
        m2[s] = MFMA(wml[s][f], M, m2[s]);
        a1[s] = MFMA(ash[s][f], S, a1[s]);
        a1[s] = MFMA(wbh[s][f], B, a1[s]);   // cols8-15: wbh*bl
        a2[s] = MFMA(asl[s][f], S, a2[s]);
        a2[s] = MFMA(wbl[s][f], B, a2[s]);
      }
    }
    {  // K-extension: bias + x coupling (hi coef only; E carries x hi|lo)
      half8 E = *(const half8*)&L.bx[p][ri];
#pragma unroll
      for (int s = 0; s < 2; ++s) {
        d1[s] = MFMA(m1h[s][4], E, d1[s]);   // cols8-15: coef-hi * x-lo
        m1[s] = MFMA(msh[s][4], E, m1[s]);
        a1[s] = MFMA(ash[s][4], E, a1[s]);
      }
    }

    // Fold partner-lane lo-sums straight into the lo accumulators
#pragma unroll
    for (int s = 0; s < 2; ++s)
#pragma unroll
      for (int r = 0; r < 4; ++r) {
        d2[s][r] += __shfl_xor(d1[s][r], 8);
        m2[s][r] += __shfl_xor(m1[s][r], 8);
        a2[s][r] += __shfl_xor(a1[s][r], 8);
      }

    // ---- Elementwise update (all lanes; junk in c>=8 stays private)
#pragma unroll
    for (int s = 0; s < 2; ++s) {
      half4 ps, mh4, ml4, bh4, bl4;
#pragma unroll
      for (int r = 0; r < 4; ++r) {
        const int i = s * 4 + r;
        float den  = d1[s][r] + d2[s][r] * INV2048;
        float preM = m1[s][r] + m2[s][r] * INV2048;
        float preA = a1[s][r] + a2[s][r] * INV2048;
        float tM = __builtin_amdgcn_rcpf(1.0f + __expf(-preM));
        float tA = __builtin_amdgcn_rcpf(1.0f + __expf(-preA));
        bb[i] = tA * bb[i] + (1.0f - tA) * spk[i];
        float Bth = 0.01f + 1.8f * bb[i];
        memv[i] = memv[i] * tM + (1.0f - tM) * den - Bth * spk[i];
        spk[i] = (memv[i] - Bth) > 0.0f ? 1.0f : 0.0f;
        ps[r] = (_Float16)spk[i];
        float v = memv[i]; _Float16 hi = (_Float16)v;
        mh4[r] = hi; ml4[r] = (_Float16)((v - (float)hi) * 2048.0f);
        v = bb[i]; hi = (_Float16)v;
        bh4[r] = hi; bl4[r] = (_Float16)((v - (float)hi) * 2048.0f);
      }
      if (act) {   // guarded stores only
        *(half4*)&L.spk[pn][w][wiH[s]] = ps;
        *(half4*)&L.mem[pn][w][wiH[s]] = mh4; *(half4*)&L.mem[pn][w][wiL[s]] = ml4;
        *(half4*)&L.bbp[pn][w][wiH[s]] = bh4; *(half4*)&L.bbp[pn][w][wiL[s]] = bl4;
      }
    }

    if (tid < 16) {   // stage next step's K-extension fragment
      const size_t tn = (t + 1 < S_LEN) ? (size_t)(t + 1) : (size_t)t;
      float2 xn = *(const float2*)&x[(tn * BATCH + bbase + (tid & 7)) * 2];
      half8 v;
      if (tid < 8) {
        v = half8{(_Float16)1.0f, (_Float16)xn.x, (_Float16)xn.y, 0, 0, 0, 0, 0};
      } else {
        _Float16 xh0 = (_Float16)xn.x, xh1 = (_Float16)xn.y;
        v = half8{0, (_Float16)((xn.x - (float)xh0) * 2048.0f),
                     (_Float16)((xn.y - (float)xh1) * 2048.0f), 0, 0, 0, 0, 0};
      }
      *(half8*)&L.bx[pn][tid * 8] = v;
    }
    __syncthreads();
  }

  // ---- Readout: out[b] = mem[b,:] @ Wlin + blin; per-block loss partial
  float part = 0.0f;
#pragma unroll
  for (int s = 0; s < 2; ++s)
#pragma unroll
    for (int r = 0; r < 4; ++r)
      part += memv[s * 4 + r] * Wlin[w * 32 + s * 16 + q * 4 + r];
  part += __shfl_xor(part, 16);
  part += __shfl_xor(part, 32);   // sum over q (same c)
  if (lane < 8) L.red[w][c] = part;
  __syncthreads();
  if (tid < 8) {
    float s = L.red[0][tid] + L.red[1][tid] + L.red[2][tid] + L.red[3][tid];
    float out = s + blin[0];
    float d = out - y[bbase + tid];
    L.red2[tid] = d * d;
  }
  __syncthreads();
  if (tid == 0) {
    float s = 0.0f;
#pragma unroll
    for (int m = 0; m < MTILE; ++m) s += L.red2[m];
    wsout[blockIdx.x] = s;
  }
}

__global__ __launch_bounds__(256) void final_reduce(const float* __restrict__ part,
                                                    float* __restrict__ out) {
  __shared__ float sh[256];
  int t = threadIdx.x;
  sh[t] = part[t];
  __syncthreads();
  for (int s = 128; s > 0; s >>= 1) {
    if (t < s) sh[t] += sh[t + s];
    __syncthreads();
  }
  if (t == 0) out[0] = sh[0] * (1.0f / (float)BATCH);
}

extern "C" void kernel_launch(void* const* d_in, const int* in_sizes, int n_in,
                              void* d_out, int out_size, void* d_ws, size_t ws_size,
                              hipStream_t stream) {
  const float* x       = (const float*)d_in[0];
  const float* y       = (const float*)d_in[1];
  const float* h0m     = (const float*)d_in[2];
  const float* h0s     = (const float*)d_in[3];
  const float* h0b     = (const float*)d_in[4];
  const float* W1x     = (const float*)d_in[5];
  const float* b1x     = (const float*)d_in[6];
  const float* WtauM   = (const float*)d_in[7];
  const float* btauM   = (const float*)d_in[8];
  const float* WtauAdp = (const float*)d_in[9];
  const float* btauAdp = (const float*)d_in[10];
  const float* Wlin    = (const float*)d_in[11];
  const float* blin    = (const float*)d_in[12];
  _Float16* wsf16 = (_Float16*)d_ws;
  float* wspart = (float*)d_ws + OFF_PART_F;

  prep<<<128, 192, 0, stream>>>(W1x, b1x, WtauM, btauM, WtauAdp, btauAdp, wsf16);
  snn_main<<<NBLK, 256, 0, stream>>>(x, y, h0m, h0s, h0b, Wlin, blin,
                                     wsf16, wspart);
  final_reduce<<<1, 256, 0, stream>>>(wspart, (float*)d_out);
}